// Round 5
// baseline (1419.624 us; speedup 1.0000x reference)
//
#include <hip/hip_runtime.h>
#include <hip/hip_bf16.h>
#include <math.h>

#define B_  8
#define N_  8192
#define S_  1024
#define K_  32
#define C0_ 64
#define NW  248          // knn worker blocks (total grid = 8 + 248 = 256 = #CUs)
#define BINS 2048
#define CCAP 256

typedef __attribute__((ext_vector_type(8))) short short8;
typedef __attribute__((ext_vector_type(4))) float f32x4;
typedef __attribute__((ext_vector_type(2))) float f32x2;

// ---- workspace layout (bytes) ----
#define WH_OFF   0          // bf16 hi weights (57344 elems)
#define WL_OFF   114688     // bf16 lo weights
#define SC_OFF   229376     // 512 f32 scale
#define SH_OFF   231424     // 512 f32 shift
#define FT_OFF   233472     // featT bf16 [B][N][64] (8 MiB)
#define NIDX_OFF 8622080    // int [B][S][32] (1 MiB)
#define PROG_OFF 9670656    // 8 ints, 64-B stride (poison 0xAA.. reads negative as int)
#define WL0E 0
#define WL1E 8192
#define WL2E 24576

__device__ __forceinline__ void split_bf16(float x, unsigned short& h, unsigned short& l) {
    __hip_bfloat16 hb = __float2bfloat16(x);
    float hf = __bfloat162float(hb);
    __hip_bfloat16 lb = __float2bfloat16(x - hf);
    h = *(unsigned short*)&hb;
    l = *(unsigned short*)&lb;
}

__device__ __forceinline__ f32x4 mfma16(short8 a, short8 b, f32x4 c) {
    return __builtin_amdgcn_mfma_f32_16x16x32_bf16(a, b, c, 0, 0, 0);
}

template<int CTRL, int RMASK>
__device__ __forceinline__ unsigned long long dpp_max_step(unsigned long long k) {
    unsigned lo = (unsigned)k, hi = (unsigned)(k >> 32);
    unsigned tlo = (unsigned)__builtin_amdgcn_update_dpp(0, (int)lo, CTRL, RMASK, 0xF, false);
    unsigned thi = (unsigned)__builtin_amdgcn_update_dpp(0, (int)hi, CTRL, RMASK, 0xF, false);
    unsigned long long t = ((unsigned long long)thi << 32) | (unsigned long long)tlo;
    return (t > k) ? t : k;
}
__device__ __forceinline__ unsigned long long wave_max_u64(unsigned long long k) {
    k = dpp_max_step<0x111, 0xF>(k);   // row_shr:1
    k = dpp_max_step<0x112, 0xF>(k);   // row_shr:2
    k = dpp_max_step<0x114, 0xF>(k);   // row_shr:4
    k = dpp_max_step<0x118, 0xF>(k);   // row_shr:8
    k = dpp_max_step<0x142, 0xA>(k);   // row_bcast:15
    k = dpp_max_step<0x143, 0xC>(k);   // row_bcast:31
    return k;
}
__device__ __forceinline__ unsigned long long umax64(unsigned long long a, unsigned long long b) {
    return (a > b) ? a : b;
}

struct KnnSh {                         // worker-role LDS view (~21 KB)
    unsigned hist[2][BINS];
    unsigned long long cand[2][CCAP];
    unsigned long long kslots[2][2][4];
    int sel[2][K_];
    unsigned wpart[2][4];
    int sBin[2], sBelow[2];
    unsigned cnt_sel[2], cnt_cand[2];
    int fallback;
};

// =====================================================================
// Fused kernel: blocks 0..7 = FPS (progress-published); blocks 8..255 =
// prep (transpose/weights/BN-fold) then pipelined kNN consuming newxyz
// as FPS produces it. 256 blocks x 1 block/CU -> all co-resident.
// =====================================================================
__global__ __launch_bounds__(512) void fused_kernel(
    const float* __restrict__ xyz, const float* __restrict__ feature,
    const float* __restrict__ w0, const float* __restrict__ w1, const float* __restrict__ w2,
    const float* __restrict__ b0, const float* __restrict__ g0, const float* __restrict__ be0,
    const float* __restrict__ m0, const float* __restrict__ v0,
    const float* __restrict__ b1, const float* __restrict__ g1, const float* __restrict__ be1,
    const float* __restrict__ m1, const float* __restrict__ v1,
    const float* __restrict__ b2, const float* __restrict__ g2, const float* __restrict__ be2,
    const float* __restrict__ m2, const float* __restrict__ v2,
    char* __restrict__ ws, float* __restrict__ out)
{
    __shared__ __align__(16) char smraw[131584];
    const int tid = threadIdx.x;
    const int bid = (int)blockIdx.x;

    if (bid < B_) {
        // =========== FPS role (exact reference semantics) ===========
        #pragma clang fp contract(off)
        const int b = bid;
        float4* xyzw = (float4*)smraw;
        unsigned long long* wredA = (unsigned long long*)(smraw + N_ * 16);
        unsigned long long* wredB = wredA + 8;
        int* prog = (int*)(ws + PROG_OFF) + b * 16;

        f32x2 px[8], py[8], pz[8], mind[8];
        const float* xb = xyz + (size_t)b * N_ * 3;
        #pragma unroll
        for (int j = 0; j < 8; ++j) {
            int n0 = (2 * j) * 512 + tid, n1 = n0 + 512;
            float x0 = xb[n0 * 3], y0 = xb[n0 * 3 + 1], z0 = xb[n0 * 3 + 2];
            float x1 = xb[n1 * 3], y1 = xb[n1 * 3 + 1], z1 = xb[n1 * 3 + 2];
            px[j] = (f32x2){x0, x1}; py[j] = (f32x2){y0, y1}; pz[j] = (f32x2){z0, z1};
            xyzw[n0] = make_float4(x0, y0, z0, 0.f);
            xyzw[n1] = make_float4(x1, y1, z1, 0.f);
            mind[j] = (f32x2){1e10f, 1e10f};
        }
        __syncthreads();

        float4 p0 = xyzw[0];
        float lx = p0.x, ly = p0.y, lz = p0.z;
        if (tid == 0) {
            float* d0 = out + (size_t)b * S_ * 3;
            d0[0] = lx; d0[1] = ly; d0[2] = lz;
        }
        const int lane = tid & 63, wid = tid >> 6;

        for (int it = 1; it < S_; ++it) {
            f32x2 lx2 = (f32x2){lx, lx}, ly2 = (f32x2){ly, ly}, lz2 = (f32x2){lz, lz};
            float bv = -1.0f; int bj = 0;
            #pragma unroll
            for (int j = 0; j < 8; ++j) {
                f32x2 dx = px[j] - lx2;                 // contract(off): exact _rn,
                f32x2 dy = py[j] - ly2;                 // eligible for v_pk_* codegen
                f32x2 dz = pz[j] - lz2;
                f32x2 t = dx * dx;
                t = t + dy * dy;
                t = t + dz * dz;
                f32x2 mv = mind[j];
                float m0v = fminf(mv.x, t.x);
                float m1v = fminf(mv.y, t.y);
                mind[j] = (f32x2){m0v, m1v};
                if (m0v > bv) { bv = m0v; bj = 2 * j; }
                if (m1v > bv) { bv = m1v; bj = 2 * j + 1; }
            }
            unsigned long long key =
                ((unsigned long long)__float_as_uint(bv) << 32) |
                (unsigned long long)(0xFFFFFFFFu - (unsigned)(bj * 512 + tid));
            key = wave_max_u64(key);
            unsigned long long* wred = (it & 1) ? wredA : wredB;
            if (lane == 63) wred[wid] = key;
            __syncthreads();
            unsigned long long g0v = umax64(wred[0], wred[1]);
            unsigned long long g1v = umax64(wred[2], wred[3]);
            unsigned long long g2v = umax64(wred[4], wred[5]);
            unsigned long long g3v = umax64(wred[6], wred[7]);
            unsigned long long g = umax64(umax64(g0v, g1v), umax64(g2v, g3v));
            int ns = (int)(0xFFFFFFFFu - (unsigned)(g & 0xFFFFFFFFull));
            float4 p = xyzw[ns];
            lx = p.x; ly = p.y; lz = p.z;
            if (tid == 0) {
                float* d0 = out + ((size_t)b * S_ + it) * 3;
                d0[0] = lx; d0[1] = ly; d0[2] = lz;
                if ((it & 7) == 7)   // publish every 8 samples (amortize fence)
                    __hip_atomic_store(prog, it + 1, __ATOMIC_RELEASE, __HIP_MEMORY_SCOPE_AGENT);
            }
        }
        if (tid == 0)
            __hip_atomic_store(prog, S_, __ATOMIC_RELEASE, __HIP_MEMORY_SCOPE_AGENT);
        return;
    }

    // =========== worker role: prep, then pipelined kNN ===========
    const int w = bid - B_;   // 0..247

    // ---- transpose slices: feature [B][64][N] -> featT bf16 [B][N][64] ----
    {
        unsigned short* th = (unsigned short*)smraw;   // [64][72]
        for (int t = w; t < 1024; t += NW) {
            int bb = t >> 7, n0 = (t & 127) * 64;
            __syncthreads();
            {
                int cg = tid >> 6, ln = tid & 63;
                const float* fb = feature + (size_t)bb * C0_ * N_;
                #pragma unroll
                for (int i = 0; i < 8; ++i) {
                    int c = cg * 8 + i;
                    __hip_bfloat16 hb = __float2bfloat16(fb[(size_t)c * N_ + n0 + ln]);
                    th[ln * 72 + c] = *(unsigned short*)&hb;
                }
            }
            __syncthreads();
            {
                int n = tid >> 3, c0 = (tid & 7) * 8;
                unsigned short* ft = (unsigned short*)(ws + FT_OFF) + ((size_t)(bb * N_ + n0 + n)) * C0_ + c0;
                *(short8*)ft = *(const short8*)(th + n * 72 + c0);
            }
        }
    }
    // ---- weight split / BN fold ----
    if (w < 112) {
        int i = w * 512 + tid;
        float x;
        if (i < WL1E)      x = w0[i];
        else if (i < WL2E) x = w1[i - WL1E];
        else               x = w2[i - WL2E];
        unsigned short h, l;
        split_bf16(x, h, l);
        ((unsigned short*)(ws + WH_OFF))[i] = h;
        ((unsigned short*)(ws + WL_OFF))[i] = l;
    } else if (w == 112) {
        int o = tid;
        if (o < 512) {
            const float *bb_, *gg, *be_, *mm, *vv; int oo;
            if (o < 128)      { bb_ = b0; gg = g0; be_ = be0; mm = m0; vv = v0; oo = o; }
            else if (o < 256) { bb_ = b1; gg = g1; be_ = be1; mm = m1; vv = v1; oo = o - 128; }
            else              { bb_ = b2; gg = g2; be_ = be2; mm = m2; vv = v2; oo = o - 256; }
            float scv = gg[oo] / sqrtf(vv[oo] + 1e-5f);
            ((float*)(ws + SC_OFF))[o] = scv;
            ((float*)(ws + SH_OFF))[o] = (bb_[oo] - mm[oo]) * scv + be_[oo];
        }
    }

    // ---- pipelined kNN: 2 queries/block-pass (one per 256-thr half) ----
    KnnSh* S = (KnnSh*)smraw;
    const int ht = tid & 255, half = tid >> 8;
    const int lane = tid & 63, widH = (tid >> 6) & 3;
    int* nidx = (int*)(ws + NIDX_OFF);

    for (int p = 0; p < 17; ++p) {
        int qA = p * (NW * 2) + w * 2;
        int q = qA + half;
        bool active = q < B_ * S_;
        int qc = active ? q : (B_ * S_ - 1);
        int s = qc >> 3, bq = qc & 7;

        // wait for FPS progress (tid 0 polls both halves' needs)
        if (tid == 0) {
            int qB = qA + 1;
            int needA = (qA < B_ * S_) ? ((qA >> 3) + 1) : 0;
            int needB = (qB < B_ * S_) ? ((qB >> 3) + 1) : 0;
            const int* pga = (const int*)(ws + PROG_OFF) + (qA & 7) * 16;
            const int* pgb = (const int*)(ws + PROG_OFF) + ((qA + 1) & 7) * 16;
            for (;;) {
                int pa = needA ? __hip_atomic_load(pga, __ATOMIC_ACQUIRE, __HIP_MEMORY_SCOPE_AGENT) : 0x7fffffff;
                int pb = needB ? __hip_atomic_load(pgb, __ATOMIC_ACQUIRE, __HIP_MEMORY_SCOPE_AGENT) : 0x7fffffff;
                if (pa >= needA && pb >= needB) break;
                __builtin_amdgcn_s_sleep(8);
            }
        }
        __syncthreads();
        if (active)   // per-thread acquire to pair with FPS release
            (void)__hip_atomic_load((const int*)(ws + PROG_OFF) + bq * 16,
                                    __ATOMIC_ACQUIRE, __HIP_MEMORY_SCOPE_AGENT);

        #pragma unroll
        for (int i = 0; i < BINS / 256; ++i) S->hist[half][ht + i * 256] = 0;
        if (ht == 0) { S->cnt_sel[half] = 0; S->cnt_cand[half] = 0; if (tid == 0) S->fallback = 0; }

        const float* qp = out + (size_t)(bq * S_ + s) * 3;
        float qx = qp[0], qy = qp[1], qz = qp[2];
        float sa = __fadd_rn(__fadd_rn(__fmul_rn(qx, qx), __fmul_rn(qy, qy)), __fmul_rn(qz, qz));

        unsigned key[32];
        const float* base = xyz + (size_t)bq * N_ * 3;
        #pragma unroll
        for (int i = 0; i < 32; ++i) {
            int n = i * 256 + ht;
            float x = base[n * 3], y = base[n * 3 + 1], z = base[n * 3 + 2];
            float sb  = __fadd_rn(__fadd_rn(__fmul_rn(x, x), __fmul_rn(y, y)), __fmul_rn(z, z));
            float dot = __fadd_rn(__fadd_rn(__fmul_rn(qx, x), __fmul_rn(qy, y)), __fmul_rn(qz, z));
            float d   = __fsub_rn(__fadd_rn(sa, sb), __fmul_rn(2.0f, dot));
            unsigned u = __float_as_uint(d);
            key[i] = u ^ (unsigned)(((int)u >> 31) | (int)0x80000000);
        }
        __syncthreads();                                          // (1)
        if (active) {
            #pragma unroll
            for (int i = 0; i < 32; ++i) atomicAdd(&S->hist[half][key[i] >> 21], 1u);
        }
        __syncthreads();                                          // (2)

        unsigned h8[8], lsum = 0;
        #pragma unroll
        for (int i = 0; i < 8; ++i) { h8[i] = S->hist[half][ht * 8 + i]; lsum += h8[i]; }
        unsigned inc = lsum;
        #pragma unroll
        for (int off = 1; off < 64; off <<= 1) {
            unsigned o = __shfl_up(inc, off);
            if (lane >= off) inc += o;
        }
        if (lane == 63) S->wpart[half][widH] = inc;
        __syncthreads();                                          // (3)
        unsigned basec = 0;
        #pragma unroll
        for (int w4 = 0; w4 < 4; ++w4) if (w4 < widH) basec += S->wpart[half][w4];
        unsigned excl = basec + inc - lsum;
        if (active && excl < (unsigned)K_ && excl + lsum >= (unsigned)K_) {
            unsigned c = excl;
            #pragma unroll
            for (int i = 0; i < 8; ++i) {
                if (c < (unsigned)K_ && c + h8[i] >= (unsigned)K_) { S->sBin[half] = ht * 8 + i; S->sBelow[half] = (int)c; }
                c += h8[i];
            }
        }
        __syncthreads();                                          // (4)
        const unsigned Bbin = (unsigned)S->sBin[half];
        const int below = S->sBelow[half];

        if (active) {
            #pragma unroll
            for (int i = 0; i < 32; ++i) {
                unsigned bin = key[i] >> 21;
                int n = i * 256 + ht;
                if (bin < Bbin) {
                    unsigned pp = atomicAdd(&S->cnt_sel[half], 1u);
                    if (pp < (unsigned)K_) S->sel[half][pp] = n;
                } else if (bin == Bbin) {
                    unsigned pp = atomicAdd(&S->cnt_cand[half], 1u);
                    if (pp < CCAP) S->cand[half][pp] = ((unsigned long long)key[i] << 32) | (unsigned)n;
                }
            }
        }
        __syncthreads();                                          // (5)
        int m = (int)S->cnt_cand[half];
        if (active && ht == 0 && m > CCAP) S->fallback = 1;
        __syncthreads();                                          // (6)

        if (!S->fallback) {
            if (widH == 0) {   // each half's wave 0
                int mtake = active ? (K_ - below) : 0;
                if (mtake < 0) mtake = 0; if (mtake > K_) mtake = K_;
                int mm = active ? m : 0;
                unsigned long long v[4];
                #pragma unroll
                for (int j = 0; j < 4; ++j) {
                    int pp = lane + j * 64;
                    v[j] = (pp < mm) ? S->cand[half][pp] : ~0ull;
                }
                for (int r = 0; r < mtake; ++r) {
                    unsigned long long loc = v[0];
                    #pragma unroll
                    for (int j = 1; j < 4; ++j) if (v[j] < loc) loc = v[j];
                    unsigned long long g = loc;
                    #pragma unroll
                    for (int off = 1; off < 64; off <<= 1) {
                        unsigned long long o = __shfl_xor(g, off);
                        if (o < g) g = o;
                    }
                    #pragma unroll
                    for (int j = 0; j < 4; ++j) if (v[j] == g) v[j] = ~0ull;
                    if (lane == 0) S->sel[half][below + r] = (int)(unsigned)(g & 0xFFFFFFFFull);
                }
            }
            __syncthreads();                                      // (7)
        } else {
            // exact fallback (massive tie pile-up): both halves run uniform 32 rounds
            unsigned bk = 0xFFFFFFFFu; int bi = 0;
            #pragma unroll
            for (int i = 0; i < 32; ++i) if (key[i] < bk) { bk = key[i]; bi = i; }
            for (int r = 0; r < K_; ++r) {
                unsigned long long pk = ((unsigned long long)bk << 32) | (unsigned)(bi * 256 + ht);
                #pragma unroll
                for (int off = 1; off < 64; off <<= 1) {
                    unsigned long long o = __shfl_xor(pk, off);
                    if (o < pk) pk = o;
                }
                if (lane == 0) S->kslots[half][r & 1][widH] = pk;
                __syncthreads();
                unsigned long long g = S->kslots[half][r & 1][0];
                #pragma unroll
                for (int w4 = 1; w4 < 4; ++w4) { unsigned long long o = S->kslots[half][r & 1][w4]; if (o < g) g = o; }
                int wn = (int)(unsigned)(g & 0xFFFFFFFFull);
                if (ht == 0) S->sel[half][r] = wn;
                if ((wn & 255) == ht) {
                    int iw = wn >> 8;
                    #pragma unroll
                    for (int ii = 0; ii < 32; ++ii) if (ii == iw) key[ii] = 0xFFFFFFFFu;
                    bk = 0xFFFFFFFFu; bi = 0;
                    #pragma unroll
                    for (int ii = 0; ii < 32; ++ii) if (key[ii] < bk) { bk = key[ii]; bi = ii; }
                }
            }
            __syncthreads();                                      // (7')
        }
        if (active && ht < K_) nidx[((size_t)(bq * S_ + s)) * K_ + ht] = S->sel[half][ht];
        __syncthreads();                                          // (8) LDS reuse
    }
}

// =====================================================================
// MLP, 4 queries (128 B-rows) per block, 256 thr / 4 waves. (unchanged)
// =====================================================================
template<int AF, int KC, bool LAST>
__device__ __forceinline__ void layer(
    const unsigned short* __restrict__ Xin, int rsi,
    unsigned short* __restrict__ Xout,
    const unsigned short* __restrict__ Wh, const unsigned short* __restrict__ Wl,
    const float* __restrict__ sc, const float* __restrict__ sh,
    float* __restrict__ outg, int wid, int ln15, int quad)
{
    const int K = KC * 32;
    f32x4 acc[AF][8];
    #pragma unroll
    for (int a = 0; a < AF; ++a)
        #pragma unroll
        for (int j = 0; j < 8; ++j) acc[a][j] = (f32x4){0.f, 0.f, 0.f, 0.f};

    #pragma unroll
    for (int kc = 0; kc < KC; ++kc) {
        const int k0 = kc * 32 + quad * 8;
        short8 bf[8];
        #pragma unroll
        for (int j = 0; j < 8; ++j)
            bf[j] = *(const short8*)(Xin + (j * 16 + ln15) * rsi + k0);
        #pragma unroll
        for (int a = 0; a < AF; ++a) {
            const int row = wid * (AF * 16) + a * 16 + ln15;
            short8 ah = *(const short8*)(Wh + (size_t)row * K + k0);
            short8 al = *(const short8*)(Wl + (size_t)row * K + k0);
            #pragma unroll
            for (int j = 0; j < 8; ++j) {
                acc[a][j] = mfma16(al, bf[j], acc[a][j]);
                acc[a][j] = mfma16(ah, bf[j], acc[a][j]);
            }
        }
    }
    #pragma unroll
    for (int a = 0; a < AF; ++a) {
        const int o4 = wid * (AF * 16) + a * 16 + quad * 4;
        f32x4 scv = *(const f32x4*)(sc + o4);
        f32x4 shv = *(const f32x4*)(sh + o4);
        if (LAST) {
            #pragma unroll
            for (int qq = 0; qq < 4; ++qq) {
                float m4[4];
                #pragma unroll
                for (int r = 0; r < 4; ++r) {
                    float v0 = fmaxf(acc[a][2 * qq][r]     * scv[r] + shv[r], 0.f);
                    float v1 = fmaxf(acc[a][2 * qq + 1][r] * scv[r] + shv[r], 0.f);
                    float mm = fmaxf(v0, v1);
                    mm = fmaxf(mm, __shfl_xor(mm, 1));
                    mm = fmaxf(mm, __shfl_xor(mm, 2));
                    mm = fmaxf(mm, __shfl_xor(mm, 4));
                    mm = fmaxf(mm, __shfl_xor(mm, 8));
                    m4[r] = mm;
                }
                if (ln15 == 0) {
                    #pragma unroll
                    for (int r = 0; r < 4; ++r)
                        outg[(size_t)(o4 + r) * S_ + qq] = m4[r];
                }
            }
        } else {
            #pragma unroll
            for (int j = 0; j < 8; ++j) {
                unsigned short pq[4];
                #pragma unroll
                for (int r = 0; r < 4; ++r) {
                    float v = fmaxf(acc[a][j][r] * scv[r] + shv[r], 0.f);
                    __hip_bfloat16 hb = __float2bfloat16(v);
                    pq[r] = *(unsigned short*)&hb;
                }
                *(unsigned long long*)(Xout + (j * 16 + ln15) * 136 + o4) = *(unsigned long long*)pq;
            }
        }
    }
}

__global__ __launch_bounds__(256, 2) void mlp_kernel(
    const char* __restrict__ ws, float* __restrict__ out)
{
    __shared__ __align__(16) unsigned short XA[128 * 136];
    __shared__ __align__(16) unsigned short XB[128 * 136];
    __shared__ int nid[128];

    const int tid = threadIdx.x;
    const int b = blockIdx.x >> 8;
    const int s0 = (blockIdx.x & 255) * 4;
    const int lane = tid & 63, wid = tid >> 6;
    const int ln15 = lane & 15, quad = lane >> 4;

    const int* nidx = (const int*)(ws + NIDX_OFF);
    if (tid < 128) nid[tid] = nidx[((size_t)(b * S_ + s0)) * K_ + tid];
    __syncthreads();

    const unsigned short* FT = (const unsigned short*)(ws + FT_OFF);
    #pragma unroll
    for (int it = 0; it < 4; ++it) {
        int idx = it * 256 + tid;
        int row = idx >> 3, slot = idx & 7;
        short8 v = *(const short8*)(FT + ((size_t)(b * N_ + nid[row])) * C0_ + slot * 8);
        *(short8*)(XA + row * 72 + slot * 8) = v;
    }
    __syncthreads();

    const unsigned short* Wh = (const unsigned short*)(ws + WH_OFF);
    const unsigned short* Wl = (const unsigned short*)(ws + WL_OFF);
    const float* sc = (const float*)(ws + SC_OFF);
    const float* sh = (const float*)(ws + SH_OFF);

    layer<2, 2, false>(XA, 72,  XB, Wh + WL0E, Wl + WL0E, sc,       sh,       nullptr, wid, ln15, quad);
    __syncthreads();
    layer<2, 4, false>(XB, 136, XA, Wh + WL1E, Wl + WL1E, sc + 128, sh + 128, nullptr, wid, ln15, quad);
    __syncthreads();
    float* outg = out + (size_t)B_ * S_ * 3 + (size_t)b * 256 * S_ + s0;
    layer<4, 4, true>(XA, 136, nullptr, Wh + WL2E, Wl + WL2E, sc + 256, sh + 256, outg, wid, ln15, quad);
}

// ======================= launch =======================
extern "C" void kernel_launch(void* const* d_in, const int* in_sizes, int n_in,
                              void* d_out, int out_size, void* d_ws, size_t ws_size,
                              hipStream_t stream) {
    const float* xyz     = (const float*)d_in[0];
    const float* feature = (const float*)d_in[1];
    const float* w0 = (const float*)d_in[2];
    const float* b0 = (const float*)d_in[3];
    const float* g0 = (const float*)d_in[4];
    const float* be0 = (const float*)d_in[5];
    const float* m0 = (const float*)d_in[6];
    const float* v0 = (const float*)d_in[7];
    const float* w1 = (const float*)d_in[8];
    const float* b1 = (const float*)d_in[9];
    const float* g1 = (const float*)d_in[10];
    const float* be1 = (const float*)d_in[11];
    const float* m1 = (const float*)d_in[12];
    const float* v1 = (const float*)d_in[13];
    const float* w2 = (const float*)d_in[14];
    const float* b2 = (const float*)d_in[15];
    const float* g2 = (const float*)d_in[16];
    const float* be2 = (const float*)d_in[17];
    const float* m2 = (const float*)d_in[18];
    const float* v2 = (const float*)d_in[19];

    float* out = (float*)d_out;
    char*  ws  = (char*)d_ws;

    void* kargs[] = {
        (void*)&xyz, (void*)&feature, (void*)&w0, (void*)&w1, (void*)&w2,
        (void*)&b0, (void*)&g0, (void*)&be0, (void*)&m0, (void*)&v0,
        (void*)&b1, (void*)&g1, (void*)&be1, (void*)&m1, (void*)&v1,
        (void*)&b2, (void*)&g2, (void*)&be2, (void*)&m2, (void*)&v2,
        (void*)&ws, (void*)&out };
    hipError_t ce = hipLaunchCooperativeKernel((void*)fused_kernel,
                                               dim3(B_ + NW), dim3(512), kargs, 0, stream);
    if (ce != hipSuccess) {
        // safe fallback: 256 blocks x 1 block/CU on 256 CUs are co-resident anyway
        fused_kernel<<<B_ + NW, 512, 0, stream>>>(xyz, feature, w0, w1, w2,
            b0, g0, be0, m0, v0, b1, g1, be1, m1, v1, b2, g2, be2, m2, v2, ws, out);
    }
    mlp_kernel<<<B_ * S_ / 4, 256, 0, stream>>>((const char*)ws, out);
}

// Round 6
// 1326.731 us; speedup vs baseline: 1.0700x; 1.0700x over previous
//
#include <hip/hip_runtime.h>
#include <hip/hip_bf16.h>
#include <math.h>

#define B_  8
#define N_  8192
#define S_  1024
#define K_  32
#define C0_ 64
#define NW  248          // knn worker blocks (total grid = 8 + 248 = 256 = #CUs)
#define BINS 2048
#define CCAP 256

typedef __attribute__((ext_vector_type(8))) short short8;
typedef __attribute__((ext_vector_type(4))) float f32x4;

// ---- workspace layout (bytes) ----
#define WH_OFF   0          // bf16 hi weights (57344 elems)
#define WL_OFF   114688     // bf16 lo weights
#define SC_OFF   229376     // 512 f32 scale
#define SH_OFF   231424     // 512 f32 shift
#define FT_OFF   233472     // featT bf16 [B][N][64] (8 MiB)
#define NIDX_OFF 8622080    // int [B][S][32] (1 MiB)
#define SLOT_OFF 9670656    // u64 [B][S][3] payload-tagged newxyz (1.5 MiB)
#define WL0E 0
#define WL1E 8192
#define WL2E 24576

__device__ __forceinline__ void split_bf16(float x, unsigned short& h, unsigned short& l) {
    __hip_bfloat16 hb = __float2bfloat16(x);
    float hf = __bfloat162float(hb);
    __hip_bfloat16 lb = __float2bfloat16(x - hf);
    h = *(unsigned short*)&hb;
    l = *(unsigned short*)&lb;
}

__device__ __forceinline__ f32x4 mfma16(short8 a, short8 b, f32x4 c) {
    return __builtin_amdgcn_mfma_f32_16x16x32_bf16(a, b, c, 0, 0, 0);
}

template<int CTRL, int RMASK>
__device__ __forceinline__ unsigned long long dpp_max_step(unsigned long long k) {
    unsigned lo = (unsigned)k, hi = (unsigned)(k >> 32);
    unsigned tlo = (unsigned)__builtin_amdgcn_update_dpp(0, (int)lo, CTRL, RMASK, 0xF, false);
    unsigned thi = (unsigned)__builtin_amdgcn_update_dpp(0, (int)hi, CTRL, RMASK, 0xF, false);
    unsigned long long t = ((unsigned long long)thi << 32) | (unsigned long long)tlo;
    return (t > k) ? t : k;
}
__device__ __forceinline__ unsigned long long wave_max_u64(unsigned long long k) {
    k = dpp_max_step<0x111, 0xF>(k);   // row_shr:1
    k = dpp_max_step<0x112, 0xF>(k);   // row_shr:2
    k = dpp_max_step<0x114, 0xF>(k);   // row_shr:4
    k = dpp_max_step<0x118, 0xF>(k);   // row_shr:8
    k = dpp_max_step<0x142, 0xA>(k);   // row_bcast:15
    k = dpp_max_step<0x143, 0xC>(k);   // row_bcast:31
    return k;
}
__device__ __forceinline__ unsigned long long umax64(unsigned long long a, unsigned long long b) {
    return (a > b) ? a : b;
}

// lgkmcnt(0)-only barrier: LDS visibility without draining vmcnt (global
// stores keep flowing in the background). 0xC07F = vmcnt all-1, expcnt all-1,
// lgkmcnt 0 on gfx9-encoding.
__device__ __forceinline__ void block_sync_lds() {
    asm volatile("" ::: "memory");
    __builtin_amdgcn_s_waitcnt(0xC07F);
    __builtin_amdgcn_s_barrier();
    asm volatile("" ::: "memory");
}

struct KnnSh {                         // worker-role LDS view (~21 KB)
    unsigned hist[2][BINS];
    unsigned long long cand[2][CCAP];
    unsigned long long kslots[2][2][4];
    int sel[2][K_];
    unsigned wpart[2][4];
    int sBin[2], sBelow[2];
    unsigned cnt_sel[2], cnt_cand[2];
    int fallback;
    float qpt[2][4];
};

// =====================================================================
// Fused kernel: blocks 0..7 = FPS (payload-atomic publishing); blocks
// 8..255 = prep (transpose/weights/BN) then pipelined kNN consuming the
// tagged slots. 256 blocks x 1 block/CU -> all co-resident.
// =====================================================================
__global__ __launch_bounds__(512) void fused_kernel(
    const float* __restrict__ xyz, const float* __restrict__ feature,
    const float* __restrict__ w0, const float* __restrict__ w1, const float* __restrict__ w2,
    const float* __restrict__ b0, const float* __restrict__ g0, const float* __restrict__ be0,
    const float* __restrict__ m0, const float* __restrict__ v0,
    const float* __restrict__ b1, const float* __restrict__ g1, const float* __restrict__ be1,
    const float* __restrict__ m1, const float* __restrict__ v1,
    const float* __restrict__ b2, const float* __restrict__ g2, const float* __restrict__ be2,
    const float* __restrict__ m2, const float* __restrict__ v2,
    char* __restrict__ ws, float* __restrict__ out)
{
    __shared__ __align__(16) char smraw[131584];
    const int tid = threadIdx.x;
    const int bid = (int)blockIdx.x;

    if (bid < B_) {
        // =========== FPS role (exact reference semantics, round-4 math) ===========
        const int b = bid;
        float4* xyzw = (float4*)smraw;
        unsigned long long* wredA = (unsigned long long*)(smraw + N_ * 16);
        unsigned long long* wredB = wredA + 8;
        unsigned long long* slots = (unsigned long long*)(ws + SLOT_OFF) + (size_t)b * S_ * 3;

        float px[16], py[16], pz[16], mind[16];
        const float* xb = xyz + (size_t)b * N_ * 3;
        #pragma unroll
        for (int j = 0; j < 16; ++j) {
            int n = j * 512 + tid;
            float x = xb[n * 3], y = xb[n * 3 + 1], z = xb[n * 3 + 2];
            px[j] = x; py[j] = y; pz[j] = z;
            xyzw[n] = make_float4(x, y, z, 0.f);
            mind[j] = 1e10f;
        }
        __syncthreads();

        float4 p0 = xyzw[0];
        float lx = p0.x, ly = p0.y, lz = p0.z;
        if (tid == 0) {
            float* d0 = out + (size_t)b * S_ * 3;
            d0[0] = lx; d0[1] = ly; d0[2] = lz;
            __hip_atomic_store(slots + 0, (unsigned long long)__float_as_uint(lx),
                               __ATOMIC_RELAXED, __HIP_MEMORY_SCOPE_AGENT);
            __hip_atomic_store(slots + 1, (unsigned long long)__float_as_uint(ly),
                               __ATOMIC_RELAXED, __HIP_MEMORY_SCOPE_AGENT);
            __hip_atomic_store(slots + 2, (unsigned long long)__float_as_uint(lz),
                               __ATOMIC_RELAXED, __HIP_MEMORY_SCOPE_AGENT);
        }
        const int lane = tid & 63, wid = tid >> 6;

        for (int it = 1; it < S_; ++it) {
            float bv = -1.0f; int bj = 0;
            #pragma unroll
            for (int j = 0; j < 16; ++j) {
                float dx = __fsub_rn(px[j], lx);
                float dy = __fsub_rn(py[j], ly);
                float dz = __fsub_rn(pz[j], lz);
                float dd = __fadd_rn(__fadd_rn(__fmul_rn(dx, dx), __fmul_rn(dy, dy)), __fmul_rn(dz, dz));
                float mj = fminf(mind[j], dd);
                mind[j] = mj;
                if (mj > bv) { bv = mj; bj = j; }
            }
            unsigned long long key =
                ((unsigned long long)__float_as_uint(bv) << 32) |
                (unsigned long long)(0xFFFFFFFFu - (unsigned)(bj * 512 + tid));
            key = wave_max_u64(key);
            unsigned long long* wred = (it & 1) ? wredA : wredB;
            if (lane == 63) wred[wid] = key;
            block_sync_lds();                       // lgkm-only: no vmcnt drain
            unsigned long long g0v = umax64(wred[0], wred[1]);
            unsigned long long g1v = umax64(wred[2], wred[3]);
            unsigned long long g2v = umax64(wred[4], wred[5]);
            unsigned long long g3v = umax64(wred[6], wred[7]);
            unsigned long long g = umax64(umax64(g0v, g1v), umax64(g2v, g3v));
            int ns = (int)(0xFFFFFFFFu - (unsigned)(g & 0xFFFFFFFFull));
            float4 p = xyzw[ns];
            lx = p.x; ly = p.y; lz = p.z;
            if (tid == 0) {
                float* d0 = out + ((size_t)b * S_ + it) * 3;
                d0[0] = lx; d0[1] = ly; d0[2] = lz;
                unsigned long long tg = ((unsigned long long)(unsigned)it) << 32;
                unsigned long long* sl = slots + (size_t)it * 3;
                __hip_atomic_store(sl + 0, tg | __float_as_uint(lx),
                                   __ATOMIC_RELAXED, __HIP_MEMORY_SCOPE_AGENT);
                __hip_atomic_store(sl + 1, tg | __float_as_uint(ly),
                                   __ATOMIC_RELAXED, __HIP_MEMORY_SCOPE_AGENT);
                __hip_atomic_store(sl + 2, tg | __float_as_uint(lz),
                                   __ATOMIC_RELAXED, __HIP_MEMORY_SCOPE_AGENT);
            }
        }
        return;
    }

    // =========== worker role: prep, then pipelined kNN ===========
    const int w = bid - B_;   // 0..247

    // ---- transpose slices: feature [B][64][N] -> featT bf16 [B][N][64] ----
    {
        unsigned short* th = (unsigned short*)smraw;   // [64][72]
        for (int t = w; t < 1024; t += NW) {
            int bb = t >> 7, n0 = (t & 127) * 64;
            __syncthreads();
            {
                int cg = tid >> 6, ln = tid & 63;
                const float* fb = feature + (size_t)bb * C0_ * N_;
                #pragma unroll
                for (int i = 0; i < 8; ++i) {
                    int c = cg * 8 + i;
                    __hip_bfloat16 hb = __float2bfloat16(fb[(size_t)c * N_ + n0 + ln]);
                    th[ln * 72 + c] = *(unsigned short*)&hb;
                }
            }
            __syncthreads();
            {
                int n = tid >> 3, c0 = (tid & 7) * 8;
                unsigned short* ft = (unsigned short*)(ws + FT_OFF) + ((size_t)(bb * N_ + n0 + n)) * C0_ + c0;
                *(short8*)ft = *(const short8*)(th + n * 72 + c0);
            }
        }
    }
    // ---- weight split / BN fold ----
    if (w < 112) {
        int i = w * 512 + tid;
        float x;
        if (i < WL1E)      x = w0[i];
        else if (i < WL2E) x = w1[i - WL1E];
        else               x = w2[i - WL2E];
        unsigned short h, l;
        split_bf16(x, h, l);
        ((unsigned short*)(ws + WH_OFF))[i] = h;
        ((unsigned short*)(ws + WL_OFF))[i] = l;
    } else if (w == 112) {
        int o = tid;
        if (o < 512) {
            const float *bb_, *gg, *be_, *mm, *vv; int oo;
            if (o < 128)      { bb_ = b0; gg = g0; be_ = be0; mm = m0; vv = v0; oo = o; }
            else if (o < 256) { bb_ = b1; gg = g1; be_ = be1; mm = m1; vv = v1; oo = o - 128; }
            else              { bb_ = b2; gg = g2; be_ = be2; mm = m2; vv = v2; oo = o - 256; }
            float scv = gg[oo] / sqrtf(vv[oo] + 1e-5f);
            ((float*)(ws + SC_OFF))[o] = scv;
            ((float*)(ws + SH_OFF))[o] = (bb_[oo] - mm[oo]) * scv + be_[oo];
        }
    }

    // ---- pipelined kNN: 2 queries/block-pass (one per 256-thr half) ----
    KnnSh* S = (KnnSh*)smraw;
    const int ht = tid & 255, half = tid >> 8;
    const int lane = tid & 63, widH = (tid >> 6) & 3;
    int* nidx = (int*)(ws + NIDX_OFF);
    const unsigned long long* slots = (const unsigned long long*)(ws + SLOT_OFF);

    for (int p = 0; p < 17; ++p) {
        int qA = p * (NW * 2) + w * 2;
        int q = qA + half;
        bool active = q < B_ * S_;
        int qc = active ? q : (B_ * S_ - 1);
        int s = qc >> 3, bq = qc & 7;

        // tid 0 polls the tagged slots for both halves' queries (payload atomics)
        if (tid == 0) {
            #pragma unroll
            for (int h = 0; h < 2; ++h) {
                int qq = qA + h;
                if (qq >= B_ * S_) continue;
                int ss = qq >> 3, bb = qq & 7;
                const unsigned long long* sl = slots + ((size_t)bb * S_ + ss) * 3;
                #pragma unroll
                for (int c = 0; c < 3; ++c) {
                    unsigned long long v;
                    for (;;) {
                        v = __hip_atomic_load(sl + c, __ATOMIC_RELAXED, __HIP_MEMORY_SCOPE_AGENT);
                        if ((int)(v >> 32) == ss) break;
                        __builtin_amdgcn_s_sleep(8);
                    }
                    S->qpt[h][c] = __uint_as_float((unsigned)v);
                }
            }
        }
        __syncthreads();

        #pragma unroll
        for (int i = 0; i < BINS / 256; ++i) S->hist[half][ht + i * 256] = 0;
        if (ht == 0) { S->cnt_sel[half] = 0; S->cnt_cand[half] = 0; if (tid == 0) S->fallback = 0; }

        float qx = S->qpt[half][0], qy = S->qpt[half][1], qz = S->qpt[half][2];
        float sa = __fadd_rn(__fadd_rn(__fmul_rn(qx, qx), __fmul_rn(qy, qy)), __fmul_rn(qz, qz));

        unsigned key[32];
        const float* base = xyz + (size_t)bq * N_ * 3;
        #pragma unroll
        for (int i = 0; i < 32; ++i) {
            int n = i * 256 + ht;
            float x = base[n * 3], y = base[n * 3 + 1], z = base[n * 3 + 2];
            float sb  = __fadd_rn(__fadd_rn(__fmul_rn(x, x), __fmul_rn(y, y)), __fmul_rn(z, z));
            float dot = __fadd_rn(__fadd_rn(__fmul_rn(qx, x), __fmul_rn(qy, y)), __fmul_rn(qz, z));
            float d   = __fsub_rn(__fadd_rn(sa, sb), __fmul_rn(2.0f, dot));
            unsigned u = __float_as_uint(d);
            key[i] = u ^ (unsigned)(((int)u >> 31) | (int)0x80000000);
        }
        __syncthreads();                                          // (1)
        if (active) {
            #pragma unroll
            for (int i = 0; i < 32; ++i) atomicAdd(&S->hist[half][key[i] >> 21], 1u);
        }
        __syncthreads();                                          // (2)

        unsigned h8[8], lsum = 0;
        #pragma unroll
        for (int i = 0; i < 8; ++i) { h8[i] = S->hist[half][ht * 8 + i]; lsum += h8[i]; }
        unsigned inc = lsum;
        #pragma unroll
        for (int off = 1; off < 64; off <<= 1) {
            unsigned o = __shfl_up(inc, off);
            if (lane >= off) inc += o;
        }
        if (lane == 63) S->wpart[half][widH] = inc;
        __syncthreads();                                          // (3)
        unsigned basec = 0;
        #pragma unroll
        for (int w4 = 0; w4 < 4; ++w4) if (w4 < widH) basec += S->wpart[half][w4];
        unsigned excl = basec + inc - lsum;
        if (active && excl < (unsigned)K_ && excl + lsum >= (unsigned)K_) {
            unsigned c = excl;
            #pragma unroll
            for (int i = 0; i < 8; ++i) {
                if (c < (unsigned)K_ && c + h8[i] >= (unsigned)K_) { S->sBin[half] = ht * 8 + i; S->sBelow[half] = (int)c; }
                c += h8[i];
            }
        }
        __syncthreads();                                          // (4)
        const unsigned Bbin = (unsigned)S->sBin[half];
        const int below = S->sBelow[half];

        if (active) {
            #pragma unroll
            for (int i = 0; i < 32; ++i) {
                unsigned bin = key[i] >> 21;
                int n = i * 256 + ht;
                if (bin < Bbin) {
                    unsigned pp = atomicAdd(&S->cnt_sel[half], 1u);
                    if (pp < (unsigned)K_) S->sel[half][pp] = n;
                } else if (bin == Bbin) {
                    unsigned pp = atomicAdd(&S->cnt_cand[half], 1u);
                    if (pp < CCAP) S->cand[half][pp] = ((unsigned long long)key[i] << 32) | (unsigned)n;
                }
            }
        }
        __syncthreads();                                          // (5)
        int m = (int)S->cnt_cand[half];
        if (active && ht == 0 && m > CCAP) S->fallback = 1;
        __syncthreads();                                          // (6)

        if (!S->fallback) {
            if (widH == 0) {   // each half's wave 0
                int mtake = active ? (K_ - below) : 0;
                if (mtake < 0) mtake = 0; if (mtake > K_) mtake = K_;
                int mm = active ? m : 0;
                unsigned long long v[4];
                #pragma unroll
                for (int j = 0; j < 4; ++j) {
                    int pp = lane + j * 64;
                    v[j] = (pp < mm) ? S->cand[half][pp] : ~0ull;
                }
                for (int r = 0; r < mtake; ++r) {
                    unsigned long long loc = v[0];
                    #pragma unroll
                    for (int j = 1; j < 4; ++j) if (v[j] < loc) loc = v[j];
                    unsigned long long g = loc;
                    #pragma unroll
                    for (int off = 1; off < 64; off <<= 1) {
                        unsigned long long o = __shfl_xor(g, off);
                        if (o < g) g = o;
                    }
                    #pragma unroll
                    for (int j = 0; j < 4; ++j) if (v[j] == g) v[j] = ~0ull;
                    if (lane == 0) S->sel[half][below + r] = (int)(unsigned)(g & 0xFFFFFFFFull);
                }
            }
            __syncthreads();                                      // (7)
        } else {
            // exact fallback (massive tie pile-up): both halves run uniform 32 rounds
            unsigned bk = 0xFFFFFFFFu; int bi = 0;
            #pragma unroll
            for (int i = 0; i < 32; ++i) if (key[i] < bk) { bk = key[i]; bi = i; }
            for (int r = 0; r < K_; ++r) {
                unsigned long long pk = ((unsigned long long)bk << 32) | (unsigned)(bi * 256 + ht);
                #pragma unroll
                for (int off = 1; off < 64; off <<= 1) {
                    unsigned long long o = __shfl_xor(pk, off);
                    if (o < pk) pk = o;
                }
                if (lane == 0) S->kslots[half][r & 1][widH] = pk;
                __syncthreads();
                unsigned long long g = S->kslots[half][r & 1][0];
                #pragma unroll
                for (int w4 = 1; w4 < 4; ++w4) { unsigned long long o = S->kslots[half][r & 1][w4]; if (o < g) g = o; }
                int wn = (int)(unsigned)(g & 0xFFFFFFFFull);
                if (ht == 0) S->sel[half][r] = wn;
                if ((wn & 255) == ht) {
                    int iw = wn >> 8;
                    #pragma unroll
                    for (int ii = 0; ii < 32; ++ii) if (ii == iw) key[ii] = 0xFFFFFFFFu;
                    bk = 0xFFFFFFFFu; bi = 0;
                    #pragma unroll
                    for (int ii = 0; ii < 32; ++ii) if (key[ii] < bk) { bk = key[ii]; bi = ii; }
                }
            }
            __syncthreads();                                      // (7')
        }
        if (active && ht < K_) nidx[((size_t)(bq * S_ + s)) * K_ + ht] = S->sel[half][ht];
        __syncthreads();                                          // (8) LDS reuse
    }
}

// =====================================================================
// MLP, 4 queries (128 B-rows) per block, 256 thr / 4 waves. (unchanged)
// =====================================================================
template<int AF, int KC, bool LAST>
__device__ __forceinline__ void layer(
    const unsigned short* __restrict__ Xin, int rsi,
    unsigned short* __restrict__ Xout,
    const unsigned short* __restrict__ Wh, const unsigned short* __restrict__ Wl,
    const float* __restrict__ sc, const float* __restrict__ sh,
    float* __restrict__ outg, int wid, int ln15, int quad)
{
    const int K = KC * 32;
    f32x4 acc[AF][8];
    #pragma unroll
    for (int a = 0; a < AF; ++a)
        #pragma unroll
        for (int j = 0; j < 8; ++j) acc[a][j] = (f32x4){0.f, 0.f, 0.f, 0.f};

    #pragma unroll
    for (int kc = 0; kc < KC; ++kc) {
        const int k0 = kc * 32 + quad * 8;
        short8 bf[8];
        #pragma unroll
        for (int j = 0; j < 8; ++j)
            bf[j] = *(const short8*)(Xin + (j * 16 + ln15) * rsi + k0);
        #pragma unroll
        for (int a = 0; a < AF; ++a) {
            const int row = wid * (AF * 16) + a * 16 + ln15;
            short8 ah = *(const short8*)(Wh + (size_t)row * K + k0);
            short8 al = *(const short8*)(Wl + (size_t)row * K + k0);
            #pragma unroll
            for (int j = 0; j < 8; ++j) {
                acc[a][j] = mfma16(al, bf[j], acc[a][j]);
                acc[a][j] = mfma16(ah, bf[j], acc[a][j]);
            }
        }
    }
    #pragma unroll
    for (int a = 0; a < AF; ++a) {
        const int o4 = wid * (AF * 16) + a * 16 + quad * 4;
        f32x4 scv = *(const f32x4*)(sc + o4);
        f32x4 shv = *(const f32x4*)(sh + o4);
        if (LAST) {
            #pragma unroll
            for (int qq = 0; qq < 4; ++qq) {
                float m4[4];
                #pragma unroll
                for (int r = 0; r < 4; ++r) {
                    float v0 = fmaxf(acc[a][2 * qq][r]     * scv[r] + shv[r], 0.f);
                    float v1 = fmaxf(acc[a][2 * qq + 1][r] * scv[r] + shv[r], 0.f);
                    float mm = fmaxf(v0, v1);
                    mm = fmaxf(mm, __shfl_xor(mm, 1));
                    mm = fmaxf(mm, __shfl_xor(mm, 2));
                    mm = fmaxf(mm, __shfl_xor(mm, 4));
                    mm = fmaxf(mm, __shfl_xor(mm, 8));
                    m4[r] = mm;
                }
                if (ln15 == 0) {
                    #pragma unroll
                    for (int r = 0; r < 4; ++r)
                        outg[(size_t)(o4 + r) * S_ + qq] = m4[r];
                }
            }
        } else {
            #pragma unroll
            for (int j = 0; j < 8; ++j) {
                unsigned short pq[4];
                #pragma unroll
                for (int r = 0; r < 4; ++r) {
                    float v = fmaxf(acc[a][j][r] * scv[r] + shv[r], 0.f);
                    __hip_bfloat16 hb = __float2bfloat16(v);
                    pq[r] = *(unsigned short*)&hb;
                }
                *(unsigned long long*)(Xout + (j * 16 + ln15) * 136 + o4) = *(unsigned long long*)pq;
            }
        }
    }
}

__global__ __launch_bounds__(256, 2) void mlp_kernel(
    const char* __restrict__ ws, float* __restrict__ out)
{
    __shared__ __align__(16) unsigned short XA[128 * 136];
    __shared__ __align__(16) unsigned short XB[128 * 136];
    __shared__ int nid[128];

    const int tid = threadIdx.x;
    const int b = blockIdx.x >> 8;
    const int s0 = (blockIdx.x & 255) * 4;
    const int lane = tid & 63, wid = tid >> 6;
    const int ln15 = lane & 15, quad = lane >> 4;

    const int* nidx = (const int*)(ws + NIDX_OFF);
    if (tid < 128) nid[tid] = nidx[((size_t)(b * S_ + s0)) * K_ + tid];
    __syncthreads();

    const unsigned short* FT = (const unsigned short*)(ws + FT_OFF);
    #pragma unroll
    for (int it = 0; it < 4; ++it) {
        int idx = it * 256 + tid;
        int row = idx >> 3, slot = idx & 7;
        short8 v = *(const short8*)(FT + ((size_t)(b * N_ + nid[row])) * C0_ + slot * 8);
        *(short8*)(XA + row * 72 + slot * 8) = v;
    }
    __syncthreads();

    const unsigned short* Wh = (const unsigned short*)(ws + WH_OFF);
    const unsigned short* Wl = (const unsigned short*)(ws + WL_OFF);
    const float* sc = (const float*)(ws + SC_OFF);
    const float* sh = (const float*)(ws + SH_OFF);

    layer<2, 2, false>(XA, 72,  XB, Wh + WL0E, Wl + WL0E, sc,       sh,       nullptr, wid, ln15, quad);
    __syncthreads();
    layer<2, 4, false>(XB, 136, XA, Wh + WL1E, Wl + WL1E, sc + 128, sh + 128, nullptr, wid, ln15, quad);
    __syncthreads();
    float* outg = out + (size_t)B_ * S_ * 3 + (size_t)b * 256 * S_ + s0;
    layer<4, 4, true>(XA, 136, nullptr, Wh + WL2E, Wl + WL2E, sc + 256, sh + 256, outg, wid, ln15, quad);
}

// ======================= launch =======================
extern "C" void kernel_launch(void* const* d_in, const int* in_sizes, int n_in,
                              void* d_out, int out_size, void* d_ws, size_t ws_size,
                              hipStream_t stream) {
    const float* xyz     = (const float*)d_in[0];
    const float* feature = (const float*)d_in[1];
    const float* w0 = (const float*)d_in[2];
    const float* b0 = (const float*)d_in[3];
    const float* g0 = (const float*)d_in[4];
    const float* be0 = (const float*)d_in[5];
    const float* m0 = (const float*)d_in[6];
    const float* v0 = (const float*)d_in[7];
    const float* w1 = (const float*)d_in[8];
    const float* b1 = (const float*)d_in[9];
    const float* g1 = (const float*)d_in[10];
    const float* be1 = (const float*)d_in[11];
    const float* m1 = (const float*)d_in[12];
    const float* v1 = (const float*)d_in[13];
    const float* w2 = (const float*)d_in[14];
    const float* b2 = (const float*)d_in[15];
    const float* g2 = (const float*)d_in[16];
    const float* be2 = (const float*)d_in[17];
    const float* m2 = (const float*)d_in[18];
    const float* v2 = (const float*)d_in[19];

    float* out = (float*)d_out;
    char*  ws  = (char*)d_ws;

    void* kargs[] = {
        (void*)&xyz, (void*)&feature, (void*)&w0, (void*)&w1, (void*)&w2,
        (void*)&b0, (void*)&g0, (void*)&be0, (void*)&m0, (void*)&v0,
        (void*)&b1, (void*)&g1, (void*)&be1, (void*)&m1, (void*)&v1,
        (void*)&b2, (void*)&g2, (void*)&be2, (void*)&m2, (void*)&v2,
        (void*)&ws, (void*)&out };
    hipError_t ce = hipLaunchCooperativeKernel((void*)fused_kernel,
                                               dim3(B_ + NW), dim3(512), kargs, 0, stream);
    if (ce != hipSuccess) {
        // safe fallback: 256 blocks x 1 block/CU on 256 CUs are co-resident anyway
        fused_kernel<<<B_ + NW, 512, 0, stream>>>(xyz, feature, w0, w1, w2,
            b0, g0, be0, m0, v0, b1, g1, be1, m1, v1, b2, g2, be2, m2, v2, ws, out);
    }
    mlp_kernel<<<B_ * S_ / 4, 256, 0, stream>>>((const char*)ws, out);
}

// Round 7
// 1255.748 us; speedup vs baseline: 1.1305x; 1.0565x over previous
//
#include <hip/hip_runtime.h>
#include <hip/hip_bf16.h>
#include <math.h>

#define B_  8
#define N_  8192
#define S_  1024
#define K_  32
#define C0_ 64
#define NK  184          // kNN worker blocks
#define NM  64           // MLP blocks   (8 + 184 + 64 = 256 = #CUs)
#define NP_KNN 23        // ceil(8192 / (184*2))
#define BINS 2048
#define CCAP 256

typedef __attribute__((ext_vector_type(8))) short short8;
typedef __attribute__((ext_vector_type(4))) float f32x4;
typedef __attribute__((ext_vector_type(2))) float f32x2;

// ---- workspace layout (bytes) ----
#define WH_OFF    0          // bf16 hi weights (57344 elems)
#define WL_OFF    114688     // bf16 lo weights
#define SC_OFF    229376     // 512 f32 scale
#define SH_OFF    231424     // 512 f32 shift
#define FT_OFF    233472     // featT bf16 [B][N][64] (8 MiB)
#define NIDX2_OFF 8622080    // u64 [B*S][32] tagged neighbor idx (2 MiB)
#define SLOT_OFF  10719232   // u64 [B][S][3] payload-tagged newxyz
#define FLAG_OFF  10915840   // u32 [NK] prep-done flags
#define WL0E 0
#define WL1E 8192
#define WL2E 24576
#define FLAG_MAGIC(w) (0x5AB00000u | (unsigned)(w))

__device__ __forceinline__ void split_bf16(float x, unsigned short& h, unsigned short& l) {
    __hip_bfloat16 hb = __float2bfloat16(x);
    float hf = __bfloat162float(hb);
    __hip_bfloat16 lb = __float2bfloat16(x - hf);
    h = *(unsigned short*)&hb;
    l = *(unsigned short*)&lb;
}

__device__ __forceinline__ f32x4 mfma16(short8 a, short8 b, f32x4 c) {
    return __builtin_amdgcn_mfma_f32_16x16x32_bf16(a, b, c, 0, 0, 0);
}

template<int CTRL, int RMASK>
__device__ __forceinline__ unsigned long long dpp_max_step(unsigned long long k) {
    unsigned lo = (unsigned)k, hi = (unsigned)(k >> 32);
    unsigned tlo = (unsigned)__builtin_amdgcn_update_dpp(0, (int)lo, CTRL, RMASK, 0xF, false);
    unsigned thi = (unsigned)__builtin_amdgcn_update_dpp(0, (int)hi, CTRL, RMASK, 0xF, false);
    unsigned long long t = ((unsigned long long)thi << 32) | (unsigned long long)tlo;
    return (t > k) ? t : k;
}
__device__ __forceinline__ unsigned long long wave_max_u64(unsigned long long k) {
    k = dpp_max_step<0x111, 0xF>(k);   // row_shr:1
    k = dpp_max_step<0x112, 0xF>(k);   // row_shr:2
    k = dpp_max_step<0x114, 0xF>(k);   // row_shr:4
    k = dpp_max_step<0x118, 0xF>(k);   // row_shr:8
    k = dpp_max_step<0x142, 0xA>(k);   // row_bcast:15
    k = dpp_max_step<0x143, 0xC>(k);   // row_bcast:31
    return k;
}
__device__ __forceinline__ unsigned long long umax64(unsigned long long a, unsigned long long b) {
    return (a > b) ? a : b;
}

// lgkmcnt(0)-only barrier: LDS visibility without draining vmcnt.
__device__ __forceinline__ void block_sync_lds() {
    asm volatile("" ::: "memory");
    __builtin_amdgcn_s_waitcnt(0xC07F);
    __builtin_amdgcn_s_barrier();
    asm volatile("" ::: "memory");
}

struct KnnSh {                         // kNN worker LDS view (~21 KB)
    unsigned hist[2][BINS];
    unsigned long long cand[2][CCAP];
    unsigned long long kslots[2][2][4];
    int sel[2][K_];
    unsigned wpart[2][4];
    int sBin[2], sBelow[2];
    unsigned cnt_sel[2], cnt_cand[2];
    int fallback;
    float qpt[2][4];
};

// ---- MFMA layer: wave widH owns AF 16-row A-tiles; B = 128 rows (4 queries) ----
template<int AF, int KC, bool LAST>
__device__ __forceinline__ void layer(
    const unsigned short* __restrict__ Xin, int rsi,
    unsigned short* __restrict__ Xout,
    const unsigned short* __restrict__ Wh, const unsigned short* __restrict__ Wl,
    const float* __restrict__ sc, const float* __restrict__ sh,
    float* __restrict__ outg, int wid, int ln15, int quad)
{
    const int K = KC * 32;
    f32x4 acc[AF][8];
    #pragma unroll
    for (int a = 0; a < AF; ++a)
        #pragma unroll
        for (int j = 0; j < 8; ++j) acc[a][j] = (f32x4){0.f, 0.f, 0.f, 0.f};

    #pragma unroll
    for (int kc = 0; kc < KC; ++kc) {
        const int k0 = kc * 32 + quad * 8;
        short8 bf[8];
        #pragma unroll
        for (int j = 0; j < 8; ++j)
            bf[j] = *(const short8*)(Xin + (j * 16 + ln15) * rsi + k0);
        #pragma unroll
        for (int a = 0; a < AF; ++a) {
            const int row = wid * (AF * 16) + a * 16 + ln15;
            short8 ah = *(const short8*)(Wh + (size_t)row * K + k0);
            short8 al = *(const short8*)(Wl + (size_t)row * K + k0);
            #pragma unroll
            for (int j = 0; j < 8; ++j) {
                acc[a][j] = mfma16(al, bf[j], acc[a][j]);
                acc[a][j] = mfma16(ah, bf[j], acc[a][j]);
            }
        }
    }
    #pragma unroll
    for (int a = 0; a < AF; ++a) {
        const int o4 = wid * (AF * 16) + a * 16 + quad * 4;
        f32x4 scv = *(const f32x4*)(sc + o4);
        f32x4 shv = *(const f32x4*)(sh + o4);
        if (LAST) {
            #pragma unroll
            for (int qq = 0; qq < 4; ++qq) {
                float m4[4];
                #pragma unroll
                for (int r = 0; r < 4; ++r) {
                    float v0 = fmaxf(acc[a][2 * qq][r]     * scv[r] + shv[r], 0.f);
                    float v1 = fmaxf(acc[a][2 * qq + 1][r] * scv[r] + shv[r], 0.f);
                    float mm = fmaxf(v0, v1);
                    mm = fmaxf(mm, __shfl_xor(mm, 1));
                    mm = fmaxf(mm, __shfl_xor(mm, 2));
                    mm = fmaxf(mm, __shfl_xor(mm, 4));
                    mm = fmaxf(mm, __shfl_xor(mm, 8));
                    m4[r] = mm;
                }
                if (ln15 == 0) {
                    #pragma unroll
                    for (int r = 0; r < 4; ++r)
                        outg[(size_t)(o4 + r) * S_ + qq] = m4[r];
                }
            }
        } else {
            #pragma unroll
            for (int j = 0; j < 8; ++j) {
                unsigned short pq[4];
                #pragma unroll
                for (int r = 0; r < 4; ++r) {
                    float v = fmaxf(acc[a][j][r] * scv[r] + shv[r], 0.f);
                    __hip_bfloat16 hb = __float2bfloat16(v);
                    pq[r] = *(unsigned short*)&hb;
                }
                *(unsigned long long*)(Xout + (j * 16 + ln15) * 136 + o4) = *(unsigned long long*)pq;
            }
        }
    }
}

// =====================================================================
// Fused kernel, 3 roles, all 256 blocks co-resident:
//   blocks 0..7     : FPS (pk-f32 dist, slot publishing only)
//   blocks 8..191   : prep (transpose/weights/BN) + pipelined kNN
//   blocks 192..255 : pipelined MLP (tagged-nidx consumers)
// =====================================================================
__global__ __launch_bounds__(512, 2) void fused_kernel(
    const float* __restrict__ xyz, const float* __restrict__ feature,
    const float* __restrict__ w0, const float* __restrict__ w1, const float* __restrict__ w2,
    const float* __restrict__ b0, const float* __restrict__ g0, const float* __restrict__ be0,
    const float* __restrict__ m0, const float* __restrict__ v0,
    const float* __restrict__ b1, const float* __restrict__ g1, const float* __restrict__ be1,
    const float* __restrict__ m1, const float* __restrict__ v1,
    const float* __restrict__ b2, const float* __restrict__ g2, const float* __restrict__ be2,
    const float* __restrict__ m2, const float* __restrict__ v2,
    char* __restrict__ ws, float* __restrict__ out)
{
    __shared__ __align__(16) char smraw[131584];
    const int tid = threadIdx.x;
    const int bid = (int)blockIdx.x;

    if (bid < B_) {
        // =========== FPS role (exact reference semantics, pk f32) ===========
        #pragma clang fp contract(off)
        const int b = bid;
        float4* xyzw = (float4*)smraw;
        unsigned long long* wredA = (unsigned long long*)(smraw + N_ * 16);
        unsigned long long* wredB = wredA + 8;
        unsigned long long* slots = (unsigned long long*)(ws + SLOT_OFF) + (size_t)b * S_ * 3;

        f32x2 px[8], py[8], pz[8], mind[8];
        const float* xb = xyz + (size_t)b * N_ * 3;
        #pragma unroll
        for (int j = 0; j < 8; ++j) {
            int n0 = (2 * j) * 512 + tid, n1 = n0 + 512;
            float x0 = xb[n0 * 3], y0 = xb[n0 * 3 + 1], z0 = xb[n0 * 3 + 2];
            float x1 = xb[n1 * 3], y1 = xb[n1 * 3 + 1], z1 = xb[n1 * 3 + 2];
            px[j] = (f32x2){x0, x1}; py[j] = (f32x2){y0, y1}; pz[j] = (f32x2){z0, z1};
            xyzw[n0] = make_float4(x0, y0, z0, 0.f);
            xyzw[n1] = make_float4(x1, y1, z1, 0.f);
            mind[j] = (f32x2){1e10f, 1e10f};
        }
        __syncthreads();

        float4 p0 = xyzw[0];
        float lx = p0.x, ly = p0.y, lz = p0.z;
        if (tid < 3) {
            float v = (tid == 0) ? lx : ((tid == 1) ? ly : lz);
            __hip_atomic_store(slots + tid, (unsigned long long)__float_as_uint(v),
                               __ATOMIC_RELAXED, __HIP_MEMORY_SCOPE_AGENT);
        }
        const int lane = tid & 63, wid = tid >> 6;

        for (int it = 1; it < S_; ++it) {
            f32x2 lx2 = (f32x2){lx, lx}, ly2 = (f32x2){ly, ly}, lz2 = (f32x2){lz, lz};
            float bv = -1.0f; int bj = 0;
            #pragma unroll
            for (int j = 0; j < 8; ++j) {
                f32x2 dx = px[j] - lx2;                 // contract(off): exact _rn per lane,
                f32x2 dy = py[j] - ly2;                 // eligible for v_pk_* codegen
                f32x2 dz = pz[j] - lz2;
                f32x2 t = dx * dx;
                t = t + dy * dy;
                t = t + dz * dz;
                f32x2 mv = mind[j];
                float m0v = fminf(mv.x, t.x);
                float m1v = fminf(mv.y, t.y);
                mind[j] = (f32x2){m0v, m1v};
                if (m0v > bv) { bv = m0v; bj = 2 * j; }
                if (m1v > bv) { bv = m1v; bj = 2 * j + 1; }
            }
            unsigned long long key =
                ((unsigned long long)__float_as_uint(bv) << 32) |
                (unsigned long long)(0xFFFFFFFFu - (unsigned)(bj * 512 + tid));
            key = wave_max_u64(key);
            unsigned long long* wred = (it & 1) ? wredA : wredB;
            if (lane == 63) wred[wid] = key;
            block_sync_lds();                       // lgkm-only: no vmcnt drain
            unsigned long long g0v = umax64(wred[0], wred[1]);
            unsigned long long g1v = umax64(wred[2], wred[3]);
            unsigned long long g2v = umax64(wred[4], wred[5]);
            unsigned long long g3v = umax64(wred[6], wred[7]);
            unsigned long long g = umax64(umax64(g0v, g1v), umax64(g2v, g3v));
            int ns = (int)(0xFFFFFFFFu - (unsigned)(g & 0xFFFFFFFFull));
            float4 p = xyzw[ns];
            lx = p.x; ly = p.y; lz = p.z;
            if (tid < 3) {   // one wave-wide tagged store publishes the sample
                float v = (tid == 0) ? lx : ((tid == 1) ? ly : lz);
                __hip_atomic_store(slots + (size_t)it * 3 + tid,
                                   (((unsigned long long)(unsigned)it) << 32) | __float_as_uint(v),
                                   __ATOMIC_RELAXED, __HIP_MEMORY_SCOPE_AGENT);
            }
        }
        return;
    }

    if (bid < B_ + NK) {
        // =========== kNN worker role: prep, release flag, pipelined kNN ===========
        const int w = bid - B_;   // 0..183

        // ---- transpose slices: feature [B][64][N] -> featT bf16 [B][N][64] ----
        {
            unsigned short* th = (unsigned short*)smraw;   // [64][72]
            for (int t = w; t < 1024; t += NK) {
                int bb = t >> 7, n0 = (t & 127) * 64;
                __syncthreads();
                {
                    int cg = tid >> 6, ln = tid & 63;
                    const float* fb = feature + (size_t)bb * C0_ * N_;
                    #pragma unroll
                    for (int i = 0; i < 8; ++i) {
                        int c = cg * 8 + i;
                        __hip_bfloat16 hb = __float2bfloat16(fb[(size_t)c * N_ + n0 + ln]);
                        th[ln * 72 + c] = *(unsigned short*)&hb;
                    }
                }
                __syncthreads();
                {
                    int n = tid >> 3, c0 = (tid & 7) * 8;
                    unsigned short* ft = (unsigned short*)(ws + FT_OFF) + ((size_t)(bb * N_ + n0 + n)) * C0_ + c0;
                    *(short8*)ft = *(const short8*)(th + n * 72 + c0);
                }
            }
        }
        // ---- weight split / BN fold ----
        if (w < 112) {
            int i = w * 512 + tid;
            float x;
            if (i < WL1E)      x = w0[i];
            else if (i < WL2E) x = w1[i - WL1E];
            else               x = w2[i - WL2E];
            unsigned short h, l;
            split_bf16(x, h, l);
            ((unsigned short*)(ws + WH_OFF))[i] = h;
            ((unsigned short*)(ws + WL_OFF))[i] = l;
        } else if (w == 112) {
            int o = tid;
            if (o < 512) {
                const float *bb_, *gg, *be_, *mm, *vv; int oo;
                if (o < 128)      { bb_ = b0; gg = g0; be_ = be0; mm = m0; vv = v0; oo = o; }
                else if (o < 256) { bb_ = b1; gg = g1; be_ = be1; mm = m1; vv = v1; oo = o - 128; }
                else              { bb_ = b2; gg = g2; be_ = be2; mm = m2; vv = v2; oo = o - 256; }
                float scv = gg[oo] / sqrtf(vv[oo] + 1e-5f);
                ((float*)(ws + SC_OFF))[o] = scv;
                ((float*)(ws + SH_OFF))[o] = (bb_[oo] - mm[oo]) * scv + be_[oo];
            }
        }
        __syncthreads();
        if (tid == 0)   // release: publishes this worker's featT/weight stores
            __hip_atomic_store((unsigned*)(ws + FLAG_OFF) + w, FLAG_MAGIC(w),
                               __ATOMIC_RELEASE, __HIP_MEMORY_SCOPE_AGENT);

        // ---- pipelined kNN: 2 queries/pass (one per 256-thr half) ----
        KnnSh* S = (KnnSh*)smraw;
        const int ht = tid & 255, half = tid >> 8;
        const int lane = tid & 63, widH = (tid >> 6) & 3;
        unsigned long long* nidx2 = (unsigned long long*)(ws + NIDX2_OFF);
        const unsigned long long* slots = (const unsigned long long*)(ws + SLOT_OFF);

        for (int p = 0; p < NP_KNN; ++p) {
            int qA = p * (NK * 2) + w * 2;
            int q = qA + half;
            bool active = q < B_ * S_;
            int qc = active ? q : (B_ * S_ - 1);
            int s = qc >> 3, bq = qc & 7;

            if (tid == 0) {
                #pragma unroll
                for (int h = 0; h < 2; ++h) {
                    int qq = qA + h;
                    if (qq >= B_ * S_) continue;
                    int ss = qq >> 3, bb = qq & 7;
                    const unsigned long long* sl = slots + ((size_t)bb * S_ + ss) * 3;
                    #pragma unroll
                    for (int c = 0; c < 3; ++c) {
                        unsigned long long v;
                        for (;;) {
                            v = __hip_atomic_load(sl + c, __ATOMIC_RELAXED, __HIP_MEMORY_SCOPE_AGENT);
                            if ((int)(v >> 32) == ss) break;
                            __builtin_amdgcn_s_sleep(8);
                        }
                        S->qpt[h][c] = __uint_as_float((unsigned)v);
                    }
                }
            }
            __syncthreads();

            // this worker owns query q -> it writes the newxyz output (exact payload bits)
            if (active && ht < 3) out[(size_t)(bq * S_ + s) * 3 + ht] = S->qpt[half][ht];

            #pragma unroll
            for (int i = 0; i < BINS / 256; ++i) S->hist[half][ht + i * 256] = 0;
            if (ht == 0) { S->cnt_sel[half] = 0; S->cnt_cand[half] = 0; if (tid == 0) S->fallback = 0; }

            float qx = S->qpt[half][0], qy = S->qpt[half][1], qz = S->qpt[half][2];
            float sa = __fadd_rn(__fadd_rn(__fmul_rn(qx, qx), __fmul_rn(qy, qy)), __fmul_rn(qz, qz));

            unsigned key[32];
            const float* base = xyz + (size_t)bq * N_ * 3;
            #pragma unroll
            for (int i = 0; i < 32; ++i) {
                int n = i * 256 + ht;
                float x = base[n * 3], y = base[n * 3 + 1], z = base[n * 3 + 2];
                float sb  = __fadd_rn(__fadd_rn(__fmul_rn(x, x), __fmul_rn(y, y)), __fmul_rn(z, z));
                float dot = __fadd_rn(__fadd_rn(__fmul_rn(qx, x), __fmul_rn(qy, y)), __fmul_rn(qz, z));
                float d   = __fsub_rn(__fadd_rn(sa, sb), __fmul_rn(2.0f, dot));
                unsigned u = __float_as_uint(d);
                key[i] = u ^ (unsigned)(((int)u >> 31) | (int)0x80000000);
            }
            __syncthreads();
            if (active) {
                #pragma unroll
                for (int i = 0; i < 32; ++i) atomicAdd(&S->hist[half][key[i] >> 21], 1u);
            }
            __syncthreads();

            unsigned h8[8], lsum = 0;
            #pragma unroll
            for (int i = 0; i < 8; ++i) { h8[i] = S->hist[half][ht * 8 + i]; lsum += h8[i]; }
            unsigned inc = lsum;
            #pragma unroll
            for (int off = 1; off < 64; off <<= 1) {
                unsigned o = __shfl_up(inc, off);
                if (lane >= off) inc += o;
            }
            if (lane == 63) S->wpart[half][widH] = inc;
            __syncthreads();
            unsigned basec = 0;
            #pragma unroll
            for (int w4 = 0; w4 < 4; ++w4) if (w4 < widH) basec += S->wpart[half][w4];
            unsigned excl = basec + inc - lsum;
            if (active && excl < (unsigned)K_ && excl + lsum >= (unsigned)K_) {
                unsigned c = excl;
                #pragma unroll
                for (int i = 0; i < 8; ++i) {
                    if (c < (unsigned)K_ && c + h8[i] >= (unsigned)K_) { S->sBin[half] = ht * 8 + i; S->sBelow[half] = (int)c; }
                    c += h8[i];
                }
            }
            __syncthreads();
            const unsigned Bbin = (unsigned)S->sBin[half];
            const int below = S->sBelow[half];

            if (active) {
                #pragma unroll
                for (int i = 0; i < 32; ++i) {
                    unsigned bin = key[i] >> 21;
                    int n = i * 256 + ht;
                    if (bin < Bbin) {
                        unsigned pp = atomicAdd(&S->cnt_sel[half], 1u);
                        if (pp < (unsigned)K_) S->sel[half][pp] = n;
                    } else if (bin == Bbin) {
                        unsigned pp = atomicAdd(&S->cnt_cand[half], 1u);
                        if (pp < CCAP) S->cand[half][pp] = ((unsigned long long)key[i] << 32) | (unsigned)n;
                    }
                }
            }
            __syncthreads();
            int m = (int)S->cnt_cand[half];
            if (active && ht == 0 && m > CCAP) S->fallback = 1;
            __syncthreads();

            if (!S->fallback) {
                if (widH == 0) {
                    int mtake = active ? (K_ - below) : 0;
                    if (mtake < 0) mtake = 0; if (mtake > K_) mtake = K_;
                    int mm = active ? m : 0;
                    unsigned long long v[4];
                    #pragma unroll
                    for (int j = 0; j < 4; ++j) {
                        int pp = lane + j * 64;
                        v[j] = (pp < mm) ? S->cand[half][pp] : ~0ull;
                    }
                    for (int r = 0; r < mtake; ++r) {
                        unsigned long long loc = v[0];
                        #pragma unroll
                        for (int j = 1; j < 4; ++j) if (v[j] < loc) loc = v[j];
                        unsigned long long g = loc;
                        #pragma unroll
                        for (int off = 1; off < 64; off <<= 1) {
                            unsigned long long o = __shfl_xor(g, off);
                            if (o < g) g = o;
                        }
                        #pragma unroll
                        for (int j = 0; j < 4; ++j) if (v[j] == g) v[j] = ~0ull;
                        if (lane == 0) S->sel[half][below + r] = (int)(unsigned)(g & 0xFFFFFFFFull);
                    }
                }
                __syncthreads();
            } else {
                unsigned bk = 0xFFFFFFFFu; int bi = 0;
                #pragma unroll
                for (int i = 0; i < 32; ++i) if (key[i] < bk) { bk = key[i]; bi = i; }
                for (int r = 0; r < K_; ++r) {
                    unsigned long long pk = ((unsigned long long)bk << 32) | (unsigned)(bi * 256 + ht);
                    #pragma unroll
                    for (int off = 1; off < 64; off <<= 1) {
                        unsigned long long o = __shfl_xor(pk, off);
                        if (o < pk) pk = o;
                    }
                    if (lane == 0) S->kslots[half][r & 1][widH] = pk;
                    __syncthreads();
                    unsigned long long g = S->kslots[half][r & 1][0];
                    #pragma unroll
                    for (int w4 = 1; w4 < 4; ++w4) { unsigned long long o = S->kslots[half][r & 1][w4]; if (o < g) g = o; }
                    int wn = (int)(unsigned)(g & 0xFFFFFFFFull);
                    if (ht == 0) S->sel[half][r] = wn;
                    if ((wn & 255) == ht) {
                        int iw = wn >> 8;
                        #pragma unroll
                        for (int ii = 0; ii < 32; ++ii) if (ii == iw) key[ii] = 0xFFFFFFFFu;
                        bk = 0xFFFFFFFFu; bi = 0;
                        #pragma unroll
                        for (int ii = 0; ii < 32; ++ii) if (key[ii] < bk) { bk = key[ii]; bi = ii; }
                    }
                }
                __syncthreads();
            }
            // publish nidx as payload-tagged atomics (tag = q)
            if (active && ht < K_)
                __hip_atomic_store(nidx2 + (size_t)q * K_ + ht,
                                   (((unsigned long long)(unsigned)q) << 32) | (unsigned)S->sel[half][ht],
                                   __ATOMIC_RELAXED, __HIP_MEMORY_SCOPE_AGENT);
            __syncthreads();   // LDS reuse next pass
        }
        return;
    }

    // =========== MLP role: 64 blocks, 32 tiles each (tile = b x 4 queries) ===========
    {
        const int m = bid - B_ - NK;   // 0..63
        const int ht = tid & 255;
        const int lane = tid & 63, widH = (tid >> 6) & 3;
        const int ln15 = lane & 15, quad = lane >> 4;

        unsigned short* XA = (unsigned short*)smraw;            // 128*136
        unsigned short* XB = (unsigned short*)(smraw + 34816);  // 128*136
        int* nid = (int*)(smraw + 69632);                       // 128

        // wait for all prep flags (relaxed spins), then one acquire fence
        {
            volatile unsigned* fl = (volatile unsigned*)(ws + FLAG_OFF);
            if (tid < NK) {
                while (__hip_atomic_load((const unsigned*)(ws + FLAG_OFF) + tid,
                                         __ATOMIC_RELAXED, __HIP_MEMORY_SCOPE_AGENT) != FLAG_MAGIC(tid))
                    __builtin_amdgcn_s_sleep(16);
            }
            (void)fl;
            __syncthreads();
            if (tid == 0) __threadfence();   // invalidate L1 + XCD L2 before reading featT/weights
            __syncthreads();
        }

        const unsigned short* FT = (const unsigned short*)(ws + FT_OFF);
        const unsigned short* Wh = (const unsigned short*)(ws + WH_OFF);
        const unsigned short* Wl = (const unsigned short*)(ws + WL_OFF);
        const float* sc = (const float*)(ws + SC_OFF);
        const float* sh = (const float*)(ws + SH_OFF);
        const unsigned long long* nidx2 = (const unsigned long long*)(ws + NIDX2_OFF);

        for (int t = m; t < 2048; t += NM) {
            int s4 = t >> 3, bq = t & 7, s0 = s4 * 4;
            // spin-load the 4 queries' tagged nidx (both halves duplicate - benign)
            if (ht < 128) {
                int qi = ht >> 5, k = ht & 31;
                int q = bq + 8 * (s0 + qi);
                const unsigned long long* ptr = nidx2 + (size_t)q * K_ + k;
                unsigned long long v;
                for (;;) {
                    v = __hip_atomic_load(ptr, __ATOMIC_RELAXED, __HIP_MEMORY_SCOPE_AGENT);
                    if ((int)(v >> 32) == q) break;
                    __builtin_amdgcn_s_sleep(8);
                }
                nid[ht] = (int)(unsigned)(v & 0xFFFFFFFFull);
            }
            __syncthreads();

            #pragma unroll
            for (int it = 0; it < 4; ++it) {
                int idx = it * 256 + ht;
                int row = idx >> 3, slot = idx & 7;
                short8 v = *(const short8*)(FT + ((size_t)(bq * N_ + nid[row])) * C0_ + slot * 8);
                *(short8*)(XA + row * 72 + slot * 8) = v;
            }
            __syncthreads();

            layer<2, 2, false>(XA, 72,  XB, Wh + WL0E, Wl + WL0E, sc,       sh,       nullptr, widH, ln15, quad);
            __syncthreads();
            layer<2, 4, false>(XB, 136, XA, Wh + WL1E, Wl + WL1E, sc + 128, sh + 128, nullptr, widH, ln15, quad);
            __syncthreads();
            float* outg = out + (size_t)B_ * S_ * 3 + (size_t)bq * 256 * S_ + s0;
            layer<4, 4, true>(XA, 136, nullptr, Wh + WL2E, Wl + WL2E, sc + 256, sh + 256, outg, widH, ln15, quad);
            __syncthreads();   // XA/XB reuse next tile
        }
    }
}

// ======================= launch =======================
extern "C" void kernel_launch(void* const* d_in, const int* in_sizes, int n_in,
                              void* d_out, int out_size, void* d_ws, size_t ws_size,
                              hipStream_t stream) {
    const float* xyz     = (const float*)d_in[0];
    const float* feature = (const float*)d_in[1];
    const float* w0 = (const float*)d_in[2];
    const float* b0 = (const float*)d_in[3];
    const float* g0 = (const float*)d_in[4];
    const float* be0 = (const float*)d_in[5];
    const float* m0 = (const float*)d_in[6];
    const float* v0 = (const float*)d_in[7];
    const float* w1 = (const float*)d_in[8];
    const float* b1 = (const float*)d_in[9];
    const float* g1 = (const float*)d_in[10];
    const float* be1 = (const float*)d_in[11];
    const float* m1 = (const float*)d_in[12];
    const float* v1 = (const float*)d_in[13];
    const float* w2 = (const float*)d_in[14];
    const float* b2 = (const float*)d_in[15];
    const float* g2 = (const float*)d_in[16];
    const float* be2 = (const float*)d_in[17];
    const float* m2 = (const float*)d_in[18];
    const float* v2 = (const float*)d_in[19];

    float* out = (float*)d_out;
    char*  ws  = (char*)d_ws;

    void* kargs[] = {
        (void*)&xyz, (void*)&feature, (void*)&w0, (void*)&w1, (void*)&w2,
        (void*)&b0, (void*)&g0, (void*)&be0, (void*)&m0, (void*)&v0,
        (void*)&b1, (void*)&g1, (void*)&be1, (void*)&m1, (void*)&v1,
        (void*)&b2, (void*)&g2, (void*)&be2, (void*)&m2, (void*)&v2,
        (void*)&ws, (void*)&out };
    hipError_t ce = hipLaunchCooperativeKernel((void*)fused_kernel,
                                               dim3(B_ + NK + NM), dim3(512), kargs, 0, stream);
    if (ce != hipSuccess) {
        // safe fallback: 256 blocks x 1 block/CU on 256 CUs are co-resident anyway
        fused_kernel<<<B_ + NK + NM, 512, 0, stream>>>(xyz, feature, w0, w1, w2,
            b0, g0, be0, m0, v0, b1, g1, be1, m1, v1, b2, g2, be2, m2, v2, ws, out);
    }
}